// Round 12
// baseline (482.144 us; speedup 1.0000x reference)
//
#include <hip/hip_runtime.h>
#include <hip/hip_cooperative_groups.h>
#include <math.h>

namespace cg = cooperative_groups;

typedef _Float16 half2v __attribute__((ext_vector_type(2)));
typedef _Float16 half4v __attribute__((ext_vector_type(4)));
typedef _Float16 half8v __attribute__((ext_vector_type(8)));
typedef float floatx4 __attribute__((ext_vector_type(4)));

static __device__ __forceinline__ half2v pack_rtz(float a, float b) {
  return __builtin_bit_cast(half2v, __builtin_amdgcn_cvt_pkrtz(a, b));
}
static __device__ __forceinline__ float dot2(half2v w, unsigned hi, unsigned lo, unsigned sel, float acc) {
  return __builtin_amdgcn_fdot2(w, __builtin_bit_cast(half2v, __builtin_amdgcn_perm(hi, lo, sel)), acc, false);
}

// ------- fused pre-pass: W transposes + x conversion -------
__global__ __launch_bounds__(256) void prep_kernel(const float* __restrict__ W1,
                                                   const float* __restrict__ W2,
                                                   const float* __restrict__ W3,
                                                   const float* __restrict__ x,
                                                   _Float16* __restrict__ Wt1,
                                                   _Float16* __restrict__ Wt2,
                                                   _Float16* __restrict__ Wt3,
                                                   _Float16* __restrict__ x16, int n8) {
  int b = blockIdx.x;
  int t = threadIdx.x;
  if (b < 256) {                       // Wt1 [256][128] <- W1 [128][256]
    if (t < 128) Wt1[(size_t)b * 128 + t] = (_Float16)W1[(size_t)t * 256 + b];
  } else if (b < 512) {                // Wt2 [256][256] <- W2 [256][256]
    int col = b - 256;
    Wt2[(size_t)col * 256 + t] = (_Float16)W2[(size_t)t * 256 + col];
  } else if (b < 576) {                // Wt3 [64][256] <- W3 [256][64]
    int col = b - 512;
    Wt3[(size_t)col * 256 + t] = (_Float16)W3[(size_t)t * 64 + col];
  } else {                             // x -> x16 (8 elems/thread)
    int i = (b - 576) * 256 + t;
    if (i < n8) {
      float4 a = ((const float4*)x)[2 * i];
      float4 c = ((const float4*)x)[2 * i + 1];
      half8v h = {(_Float16)a.x, (_Float16)a.y, (_Float16)a.z, (_Float16)a.w,
                  (_Float16)c.x, (_Float16)c.y, (_Float16)c.z, (_Float16)c.w};
      ((half8v*)x16)[i] = h;
    }
  }
}

// ------- single cooperative CSR build: zero+count+scan+scatter -------
// 256 blocks x 256 threads (1 block/CU -> co-residency guaranteed).
// N=50000 -> 49 scan chunks of 1024 (<=64, fits one-wave chunk-sum scan).
__global__ __launch_bounds__(256) void csr_coop_kernel(const int* __restrict__ ei, int E, int N,
                                                       int* __restrict__ counts,
                                                       int* __restrict__ offsets,
                                                       int* __restrict__ cursor,
                                                       int* __restrict__ blocksums,
                                                       int* __restrict__ src_csr) {
  cg::grid_group grid = cg::this_grid();
  const int tid = threadIdx.x, b = blockIdx.x;
  const int gt = b * 256 + tid, gs = gridDim.x * 256;
  const int ET = E + N;
  // Z: zero counts
  for (int i = gt; i < N; i += gs) counts[i] = 0;
  grid.sync();
  // C: count degrees
  for (int e = gt; e < ET; e += gs) {
    int d = (e < E) ? ei[E + e] : (e - E);
    atomicAdd(&counts[d], 1);
  }
  grid.sync();
  // S1: per-1024-chunk exclusive scan (4 elems/thread)
  const int NB1 = (N + 1023) >> 10;
  if (b < NB1) {
    __shared__ int wsum[4];
    int base = b << 10;
    int v[4]; int s = 0;
    #pragma unroll
    for (int j = 0; j < 4; ++j) {
      int i = base + tid * 4 + j;
      v[j] = (i < N) ? counts[i] : 0;
      s += v[j];
    }
    int lane = tid & 63, wid = tid >> 6;
    int x = s;
    #pragma unroll
    for (int off = 1; off < 64; off <<= 1) {
      int t2 = __shfl_up(x, off);
      if (lane >= off) x += t2;
    }
    if (lane == 63) wsum[wid] = x;
    __syncthreads();
    int wbase = 0;
    #pragma unroll
    for (int wdx = 0; wdx < 4; ++wdx) if (wdx < wid) wbase += wsum[wdx];
    int run = wbase + x - s;          // exclusive prefix for this thread
    #pragma unroll
    for (int j = 0; j < 4; ++j) {
      int i = base + tid * 4 + j;
      if (i < N) offsets[i] = run;
      run += v[j];
    }
    if (tid == 255) blocksums[b] = run;   // chunk total
  }
  grid.sync();
  // S2: one-wave scan of chunk totals (NB1 <= 64)
  if (b == 0 && tid < 64) {
    int v2 = (tid < NB1) ? blocksums[tid] : 0;
    int x = v2;
    #pragma unroll
    for (int off = 1; off < 64; off <<= 1) {
      int t2 = __shfl_up(x, off);
      if (tid >= off) x += t2;
    }
    if (tid < NB1) blocksums[tid] = x - v2;  // exclusive chunk base
    if (tid == 63) offsets[N] = x;           // grand total
  }
  grid.sync();
  // S3: add chunk bases; init cursor
  for (int i = gt; i < N; i += gs) {
    int o = offsets[i] + blocksums[i >> 10];
    offsets[i] = o;
    cursor[i] = o;
  }
  grid.sync();
  // SC: scatter src in dst-sorted order
  for (int e = gt; e < ET; e += gs) {
    int s2 = (e < E) ? ei[e] : (e - E);
    int d = (e < E) ? ei[E + e] : (e - E);
    int pos = atomicAdd(&cursor[d], 1);
    src_csr[pos] = s2;
  }
}

// ---------------- all-f16 MFMA GEMM + fused alpha epilogue ----------------
// Operand-swapped: A-operand = weight cols, B-operand = node rows.
// D mapping: node = lane&15, wcol = ct*16 + (lane>>4)*4 + reg (contiguous half4 stores).
template <int NT, int H>   // Nc = NT*16
__global__ __launch_bounds__(256) void gemm16_kernel(const _Float16* __restrict__ A,
                                                     const _Float16* __restrict__ Wt,
                                                     const float* __restrict__ als,
                                                     const float* __restrict__ ald,
                                                     _Float16* __restrict__ out16,
                                                     float* __restrict__ asrc,
                                                     float* __restrict__ adst,
                                                     int M, int K) {
  constexpr int Nc = NT * 16;
  constexpr int BM = 128, BK = 32;
  constexpr int CPH = NT / H;
  __shared__ _Float16 As[BM][40];
  __shared__ _Float16 Ws[Nc][40];
  int bm = blockIdx.x * BM;
  int tid = threadIdx.x;
  int w = tid >> 6, l = tid & 63;
  int lr = l & 15, lg = l >> 4;

  floatx4 acc[2][NT];
  #pragma unroll
  for (int nf = 0; nf < 2; ++nf)
    #pragma unroll
    for (int ct = 0; ct < NT; ++ct) acc[nf][ct] = (floatx4){0.f, 0.f, 0.f, 0.f};

  for (int k0 = 0; k0 < K; k0 += BK) {
    #pragma unroll
    for (int i = 0; i < 2; ++i) {
      int idx = tid + i * 256;
      int r = idx >> 2, c8 = idx & 3;
      int gr = bm + r;
      half8v hv = {(_Float16)0, (_Float16)0, (_Float16)0, (_Float16)0,
                   (_Float16)0, (_Float16)0, (_Float16)0, (_Float16)0};
      if (gr < M) hv = *(const half8v*)&A[(size_t)gr * K + k0 + c8 * 8];
      *(half8v*)&As[r][c8 * 8] = hv;
    }
    #pragma unroll
    for (int i = 0; i < NT / 4; ++i) {
      int idx = tid + i * 256;
      int col = idx >> 2, c8 = idx & 3;
      *(half8v*)&Ws[col][c8 * 8] = *(const half8v*)&Wt[(size_t)col * K + k0 + c8 * 8];
    }
    __syncthreads();
    half8v b0 = *(half8v*)&As[w * 32 + lr][lg * 8];
    half8v b1 = *(half8v*)&As[w * 32 + 16 + lr][lg * 8];
    #pragma unroll
    for (int ct = 0; ct < NT; ++ct) {
      half8v a = *(half8v*)&Ws[ct * 16 + lr][lg * 8];
      acc[0][ct] = __builtin_amdgcn_mfma_f32_16x16x32_f16(a, b0, acc[0][ct], 0, 0, 0);
      acc[1][ct] = __builtin_amdgcn_mfma_f32_16x16x32_f16(a, b1, acc[1][ct], 0, 0, 0);
    }
    __syncthreads();
  }
  float4 als4[NT], ald4[NT];
  #pragma unroll
  for (int ct = 0; ct < NT; ++ct) {
    als4[ct] = *(const float4*)&als[ct * 16 + lg * 4];
    ald4[ct] = *(const float4*)&ald[ct * 16 + lg * 4];
  }
  #pragma unroll
  for (int nf = 0; nf < 2; ++nf) {
    int node = bm + w * 32 + nf * 16 + lr;
    float ps[H], pd[H];
    #pragma unroll
    for (int hh = 0; hh < H; ++hh) {
      float s = 0.f, d = 0.f;
      #pragma unroll
      for (int c2 = 0; c2 < CPH; ++c2) {
        int ct = hh * CPH + c2;
        s += acc[nf][ct][0] * als4[ct].x + acc[nf][ct][1] * als4[ct].y +
             acc[nf][ct][2] * als4[ct].z + acc[nf][ct][3] * als4[ct].w;
        d += acc[nf][ct][0] * ald4[ct].x + acc[nf][ct][1] * ald4[ct].y +
             acc[nf][ct][2] * ald4[ct].z + acc[nf][ct][3] * ald4[ct].w;
      }
      ps[hh] = s; pd[hh] = d;
    }
    #pragma unroll
    for (int hh = 0; hh < H; ++hh) {
      ps[hh] += __shfl_xor(ps[hh], 16); ps[hh] += __shfl_xor(ps[hh], 32);
      pd[hh] += __shfl_xor(pd[hh], 16); pd[hh] += __shfl_xor(pd[hh], 32);
    }
    if (node < M) {
      if (lg == 0) {
        #pragma unroll
        for (int hh = 0; hh < H; ++hh) asrc[node * H + hh] = ps[hh];
      } else if (lg == 1) {
        #pragma unroll
        for (int hh = 0; hh < H; ++hh) adst[node * H + hh] = pd[hh];
      }
      #pragma unroll
      for (int ct = 0; ct < NT; ++ct) {
        half4v hv = {(_Float16)acc[nf][ct][0], (_Float16)acc[nf][ct][1],
                     (_Float16)acc[nf][ct][2], (_Float16)acc[nf][ct][3]};
        *(half4v*)&out16[(size_t)node * Nc + ct * 16 + lg * 4] = hv;
      }
    }
  }
}

// ---------------- fused score + aggregation + LayerNorm + ELU, H=4 ----------
__global__ __launch_bounds__(128) void agg4_ln_kernel(const _Float16* __restrict__ h16,
                                                      const float* __restrict__ asrc,
                                                      const float* __restrict__ adst,
                                                      const int* __restrict__ offsets,
                                                      const int* __restrict__ src_csr,
                                                      const float* __restrict__ bias,
                                                      const float* __restrict__ g,
                                                      const float* __restrict__ be,
                                                      _Float16* __restrict__ out, int n) {
  int wid = threadIdx.x >> 6, lane = threadIdx.x & 63;
  int node = blockIdx.x * 2 + wid;
  if (node >= n) return;
  int start = offsets[node], end = offsets[node + 1];
  int hl = lane >> 5;
  int l5 = lane & 31;
  int head = l5 >> 3;
  float adh = adst[node * 4 + head];
  const uint4* h4 = (const uint4*)h16;
  const half2v ones = {(_Float16)1.f, (_Float16)1.f};
  float acc[8] = {0.f, 0.f, 0.f, 0.f, 0.f, 0.f, 0.f, 0.f};
  float denom = 0.f;
  int i = start + hl;
  for (; i + 6 < end; i += 8) {
    int s0 = src_csr[i], s1 = src_csr[i + 2], s2 = src_csr[i + 4], s3 = src_csr[i + 6];
    uint4 x0 = h4[(size_t)s0 * 32 + l5];
    uint4 x1 = h4[(size_t)s1 * 32 + l5];
    uint4 x2 = h4[(size_t)s2 * 32 + l5];
    uint4 x3 = h4[(size_t)s3 * 32 + l5];
    float sc0 = asrc[s0 * 4 + head] + adh;
    float sc1 = asrc[s1 * 4 + head] + adh;
    float sc2 = asrc[s2 * 4 + head] + adh;
    float sc3 = asrc[s3 * 4 + head] + adh;
    sc0 = fmaxf(sc0, 0.2f * sc0);
    sc1 = fmaxf(sc1, 0.2f * sc1);
    sc2 = fmaxf(sc2, 0.2f * sc2);
    sc3 = fmaxf(sc3, 0.2f * sc3);
    half2v wa = pack_rtz(__expf(sc0), __expf(sc1));
    half2v wb = pack_rtz(__expf(sc2), __expf(sc3));
    denom = __builtin_amdgcn_fdot2(wa, ones, denom, false);
    denom = __builtin_amdgcn_fdot2(wb, ones, denom, false);
    acc[0] = dot2(wa, x1.x, x0.x, 0x05040100u, acc[0]);
    acc[1] = dot2(wa, x1.x, x0.x, 0x07060302u, acc[1]);
    acc[2] = dot2(wa, x1.y, x0.y, 0x05040100u, acc[2]);
    acc[3] = dot2(wa, x1.y, x0.y, 0x07060302u, acc[3]);
    acc[4] = dot2(wa, x1.z, x0.z, 0x05040100u, acc[4]);
    acc[5] = dot2(wa, x1.z, x0.z, 0x07060302u, acc[5]);
    acc[6] = dot2(wa, x1.w, x0.w, 0x05040100u, acc[6]);
    acc[7] = dot2(wa, x1.w, x0.w, 0x07060302u, acc[7]);
    acc[0] = dot2(wb, x3.x, x2.x, 0x05040100u, acc[0]);
    acc[1] = dot2(wb, x3.x, x2.x, 0x07060302u, acc[1]);
    acc[2] = dot2(wb, x3.y, x2.y, 0x05040100u, acc[2]);
    acc[3] = dot2(wb, x3.y, x2.y, 0x07060302u, acc[3]);
    acc[4] = dot2(wb, x3.z, x2.z, 0x05040100u, acc[4]);
    acc[5] = dot2(wb, x3.z, x2.z, 0x07060302u, acc[5]);
    acc[6] = dot2(wb, x3.w, x2.w, 0x05040100u, acc[6]);
    acc[7] = dot2(wb, x3.w, x2.w, 0x07060302u, acc[7]);
  }
  for (; i + 2 < end; i += 4) {
    int s0 = src_csr[i], s1 = src_csr[i + 2];
    uint4 x0 = h4[(size_t)s0 * 32 + l5];
    uint4 x1 = h4[(size_t)s1 * 32 + l5];
    float sc0 = asrc[s0 * 4 + head] + adh;
    float sc1 = asrc[s1 * 4 + head] + adh;
    sc0 = fmaxf(sc0, 0.2f * sc0);
    sc1 = fmaxf(sc1, 0.2f * sc1);
    half2v wa = pack_rtz(__expf(sc0), __expf(sc1));
    denom = __builtin_amdgcn_fdot2(wa, ones, denom, false);
    acc[0] = dot2(wa, x1.x, x0.x, 0x05040100u, acc[0]);
    acc[1] = dot2(wa, x1.x, x0.x, 0x07060302u, acc[1]);
    acc[2] = dot2(wa, x1.y, x0.y, 0x05040100u, acc[2]);
    acc[3] = dot2(wa, x1.y, x0.y, 0x07060302u, acc[3]);
    acc[4] = dot2(wa, x1.z, x0.z, 0x05040100u, acc[4]);
    acc[5] = dot2(wa, x1.z, x0.z, 0x07060302u, acc[5]);
    acc[6] = dot2(wa, x1.w, x0.w, 0x05040100u, acc[6]);
    acc[7] = dot2(wa, x1.w, x0.w, 0x07060302u, acc[7]);
  }
  if (i < end) {
    int s0 = src_csr[i];
    uint4 x0 = h4[(size_t)s0 * 32 + l5];
    float sc0 = asrc[s0 * 4 + head] + adh;
    sc0 = fmaxf(sc0, 0.2f * sc0);
    half2v wa = pack_rtz(__expf(sc0), 0.f);
    denom = __builtin_amdgcn_fdot2(wa, ones, denom, false);
    acc[0] = dot2(wa, x0.x, x0.x, 0x05040100u, acc[0]);
    acc[1] = dot2(wa, x0.x, x0.x, 0x07060302u, acc[1]);
    acc[2] = dot2(wa, x0.y, x0.y, 0x05040100u, acc[2]);
    acc[3] = dot2(wa, x0.y, x0.y, 0x07060302u, acc[3]);
    acc[4] = dot2(wa, x0.z, x0.z, 0x05040100u, acc[4]);
    acc[5] = dot2(wa, x0.z, x0.z, 0x07060302u, acc[5]);
    acc[6] = dot2(wa, x0.w, x0.w, 0x05040100u, acc[6]);
    acc[7] = dot2(wa, x0.w, x0.w, 0x07060302u, acc[7]);
  }
  #pragma unroll
  for (int j = 0; j < 8; ++j) acc[j] += __shfl_xor(acc[j], 32);
  denom += __shfl_xor(denom, 32);
  float inv = 1.f / denom;
  float o[8];
  float4 b0 = *(const float4*)&bias[l5 * 8];
  float4 b1 = *(const float4*)&bias[l5 * 8 + 4];
  o[0] = acc[0] * inv + b0.x; o[1] = acc[1] * inv + b0.y;
  o[2] = acc[2] * inv + b0.z; o[3] = acc[3] * inv + b0.w;
  o[4] = acc[4] * inv + b1.x; o[5] = acc[5] * inv + b1.y;
  o[6] = acc[6] * inv + b1.z; o[7] = acc[7] * inv + b1.w;
  float s = 0.f;
  #pragma unroll
  for (int j = 0; j < 8; ++j) s += o[j];
  #pragma unroll
  for (int off = 16; off; off >>= 1) s += __shfl_xor(s, off);
  float mu = s * (1.f / 256.f);
  float var = 0.f;
  #pragma unroll
  for (int j = 0; j < 8; ++j) { float d = o[j] - mu; var += d * d; }
  #pragma unroll
  for (int off = 16; off; off >>= 1) var += __shfl_xor(var, off);
  float r = rsqrtf(var * (1.f / 256.f) + 1e-5f);
  float4 g0 = *(const float4*)&g[l5 * 8];
  float4 g1 = *(const float4*)&g[l5 * 8 + 4];
  float4 e0 = *(const float4*)&be[l5 * 8];
  float4 e1 = *(const float4*)&be[l5 * 8 + 4];
  float gg[8] = {g0.x, g0.y, g0.z, g0.w, g1.x, g1.y, g1.z, g1.w};
  float ee[8] = {e0.x, e0.y, e0.z, e0.w, e1.x, e1.y, e1.z, e1.w};
  if (hl == 0) {
    half8v yv;
    #pragma unroll
    for (int j = 0; j < 8; ++j) {
      float t = (o[j] - mu) * r * gg[j] + ee[j];
      t = (t > 0.f) ? t : expm1f(t);
      yv[j] = (_Float16)t;
    }
    *(half8v*)&out[(size_t)node * 256 + l5 * 8] = yv;
  }
}

// ---------------- fused score + aggregation + LayerNorm + ELU, H=1 ----------
__global__ __launch_bounds__(128) void agg1_ln_kernel(const _Float16* __restrict__ h16,
                                                      const float* __restrict__ asrc,
                                                      const float* __restrict__ adst,
                                                      const int* __restrict__ offsets,
                                                      const int* __restrict__ src_csr,
                                                      const float* __restrict__ bias,
                                                      const float* __restrict__ g,
                                                      const float* __restrict__ be,
                                                      float* __restrict__ out, int n) {
  int wid = threadIdx.x >> 6, lane = threadIdx.x & 63;
  int node = blockIdx.x * 2 + wid;
  if (node >= n) return;
  int start = offsets[node], end = offsets[node + 1];
  int qi = lane >> 4;
  int ql = lane & 15;
  float adh = adst[node];
  const uint2* h2 = (const uint2*)h16;
  const half2v ones = {(_Float16)1.f, (_Float16)1.f};
  float acc[4] = {0.f, 0.f, 0.f, 0.f};
  float denom = 0.f;
  int i = start + qi;
  for (; i + 12 < end; i += 16) {
    int s0 = src_csr[i], s1 = src_csr[i + 4], s2 = src_csr[i + 8], s3 = src_csr[i + 12];
    uint2 x0 = h2[(size_t)s0 * 16 + ql];
    uint2 x1 = h2[(size_t)s1 * 16 + ql];
    uint2 x2 = h2[(size_t)s2 * 16 + ql];
    uint2 x3 = h2[(size_t)s3 * 16 + ql];
    float sc0 = asrc[s0] + adh;
    float sc1 = asrc[s1] + adh;
    float sc2 = asrc[s2] + adh;
    float sc3 = asrc[s3] + adh;
    sc0 = fmaxf(sc0, 0.2f * sc0);
    sc1 = fmaxf(sc1, 0.2f * sc1);
    sc2 = fmaxf(sc2, 0.2f * sc2);
    sc3 = fmaxf(sc3, 0.2f * sc3);
    half2v wa = pack_rtz(__expf(sc0), __expf(sc1));
    half2v wb = pack_rtz(__expf(sc2), __expf(sc3));
    denom = __builtin_amdgcn_fdot2(wa, ones, denom, false);
    denom = __builtin_amdgcn_fdot2(wb, ones, denom, false);
    acc[0] = dot2(wa, x1.x, x0.x, 0x05040100u, acc[0]);
    acc[1] = dot2(wa, x1.x, x0.x, 0x07060302u, acc[1]);
    acc[2] = dot2(wa, x1.y, x0.y, 0x05040100u, acc[2]);
    acc[3] = dot2(wa, x1.y, x0.y, 0x07060302u, acc[3]);
    acc[0] = dot2(wb, x3.x, x2.x, 0x05040100u, acc[0]);
    acc[1] = dot2(wb, x3.x, x2.x, 0x07060302u, acc[1]);
    acc[2] = dot2(wb, x3.y, x2.y, 0x05040100u, acc[2]);
    acc[3] = dot2(wb, x3.y, x2.y, 0x07060302u, acc[3]);
  }
  for (; i + 4 < end; i += 8) {
    int s0 = src_csr[i], s1 = src_csr[i + 4];
    uint2 x0 = h2[(size_t)s0 * 16 + ql];
    uint2 x1 = h2[(size_t)s1 * 16 + ql];
    float sc0 = asrc[s0] + adh;
    float sc1 = asrc[s1] + adh;
    sc0 = fmaxf(sc0, 0.2f * sc0);
    sc1 = fmaxf(sc1, 0.2f * sc1);
    half2v wa = pack_rtz(__expf(sc0), __expf(sc1));
    denom = __builtin_amdgcn_fdot2(wa, ones, denom, false);
    acc[0] = dot2(wa, x1.x, x0.x, 0x05040100u, acc[0]);
    acc[1] = dot2(wa, x1.x, x0.x, 0x07060302u, acc[1]);
    acc[2] = dot2(wa, x1.y, x0.y, 0x05040100u, acc[2]);
    acc[3] = dot2(wa, x1.y, x0.y, 0x07060302u, acc[3]);
  }
  if (i < end) {
    int s0 = src_csr[i];
    uint2 x0 = h2[(size_t)s0 * 16 + ql];
    float sc0 = asrc[s0] + adh;
    sc0 = fmaxf(sc0, 0.2f * sc0);
    half2v wa = pack_rtz(__expf(sc0), 0.f);
    denom = __builtin_amdgcn_fdot2(wa, ones, denom, false);
    acc[0] = dot2(wa, x0.x, x0.x, 0x05040100u, acc[0]);
    acc[1] = dot2(wa, x0.x, x0.x, 0x07060302u, acc[1]);
    acc[2] = dot2(wa, x0.y, x0.y, 0x05040100u, acc[2]);
    acc[3] = dot2(wa, x0.y, x0.y, 0x07060302u, acc[3]);
  }
  #pragma unroll
  for (int off = 32; off >= 16; off >>= 1) {
    #pragma unroll
    for (int j = 0; j < 4; ++j) acc[j] += __shfl_xor(acc[j], off);
    denom += __shfl_xor(denom, off);
  }
  float inv = 1.f / denom;
  float4 b4 = *(const float4*)&bias[ql * 4];
  float o[4];
  o[0] = acc[0] * inv + b4.x; o[1] = acc[1] * inv + b4.y;
  o[2] = acc[2] * inv + b4.z; o[3] = acc[3] * inv + b4.w;
  float s = o[0] + o[1] + o[2] + o[3];
  #pragma unroll
  for (int off = 8; off; off >>= 1) s += __shfl_xor(s, off);
  float mu = s * (1.f / 64.f);
  float var = 0.f;
  #pragma unroll
  for (int j = 0; j < 4; ++j) { float d = o[j] - mu; var += d * d; }
  #pragma unroll
  for (int off = 8; off; off >>= 1) var += __shfl_xor(var, off);
  float r = rsqrtf(var * (1.f / 64.f) + 1e-5f);
  float4 g4 = *(const float4*)&g[ql * 4];
  float4 e4 = *(const float4*)&be[ql * 4];
  float gg[4] = {g4.x, g4.y, g4.z, g4.w};
  float ee[4] = {e4.x, e4.y, e4.z, e4.w};
  float y[4];
  #pragma unroll
  for (int j = 0; j < 4; ++j) {
    float t = (o[j] - mu) * r * gg[j] + ee[j];
    y[j] = (t > 0.f) ? t : expm1f(t);
  }
  if (qi == 0) {
    *(float4*)&out[(size_t)node * 64 + ql * 4] = make_float4(y[0], y[1], y[2], y[3]);
  }
}

// ---------------- fused pool + MLP head (batch sorted; 1024-thr pool) --------
__global__ __launch_bounds__(1024) void graph_head_kernel(const float* __restrict__ h,
                                                          const int* __restrict__ batch, int N,
                                                          const float* __restrict__ Wg,
                                                          const float* __restrict__ bg,
                                                          const float* __restrict__ Wg2,
                                                          const float* __restrict__ bg2,
                                                          const float* __restrict__ Wo,
                                                          const float* __restrict__ bo,
                                                          float* __restrict__ out) {
  __shared__ int bounds[2];
  __shared__ float part[64][16][4];
  __shared__ float gm[64];
  __shared__ float z1[128];
  __shared__ float z2[64];
  int g = blockIdx.x;
  int tid = threadIdx.x;
  if (tid < 2) {
    int target = g + tid;
    int lo = 0, hi = N;
    while (lo < hi) {
      int mid = (lo + hi) >> 1;
      if (batch[mid] < target) lo = mid + 1; else hi = mid;
    }
    bounds[tid] = lo;
  }
  __syncthreads();
  int lo = bounds[0], hi = bounds[1];
  int sub = tid >> 4, cq = tid & 15;
  float4 acc = make_float4(0.f, 0.f, 0.f, 0.f);
  for (int r = lo + sub; r < hi; r += 64) {
    float4 v = *(const float4*)&h[(size_t)r * 64 + cq * 4];
    acc.x += v.x; acc.y += v.y; acc.z += v.z; acc.w += v.w;
  }
  part[sub][cq][0] = acc.x; part[sub][cq][1] = acc.y;
  part[sub][cq][2] = acc.z; part[sub][cq][3] = acc.w;
  __syncthreads();
  #pragma unroll
  for (int st = 32; st >= 1; st >>= 1) {
    if (sub < st) {
      #pragma unroll
      for (int j = 0; j < 4; ++j) part[sub][cq][j] += part[sub + st][cq][j];
    }
    __syncthreads();
  }
  if (tid < 16) {
    float invc = 1.f / fmaxf((float)(hi - lo), 1.f);
    #pragma unroll
    for (int j = 0; j < 4; ++j) gm[tid * 4 + j] = part[0][tid][j] * invc;
  }
  __syncthreads();
  if (tid < 128) {
    float a = bg[tid];
    for (int k = 0; k < 64; ++k) a += gm[k] * Wg[k * 128 + tid];
    z1[tid] = fmaxf(a, 0.f);
  }
  __syncthreads();
  if (tid < 64) {
    float a = bg2[tid];
    for (int k = 0; k < 128; ++k) a += z1[k] * Wg2[k * 64 + tid];
    z2[tid] = fmaxf(a, 0.f);
  }
  __syncthreads();
  if (tid < 5) {
    float a = bo[tid];
    for (int k = 0; k < 64; ++k) a += z2[k] * Wo[k * 5 + tid];
    out[g * 5 + tid] = a;
  }
}

// ---------------- launch ----------------
extern "C" void kernel_launch(void* const* d_in, const int* in_sizes, int n_in,
                              void* d_out, int out_size, void* d_ws, size_t ws_size,
                              hipStream_t stream) {
  const float* x   = (const float*)d_in[0];
  const int* ei    = (const int*)d_in[1];
  const int* batch = (const int*)d_in[2];
  const float* W1  = (const float*)d_in[3];
  const float* a1s = (const float*)d_in[4];
  const float* a1d = (const float*)d_in[5];
  const float* b1  = (const float*)d_in[6];
  const float* g1  = (const float*)d_in[7];
  const float* be1 = (const float*)d_in[8];
  const float* W2  = (const float*)d_in[9];
  const float* a2s = (const float*)d_in[10];
  const float* a2d = (const float*)d_in[11];
  const float* b2  = (const float*)d_in[12];
  const float* g2  = (const float*)d_in[13];
  const float* be2 = (const float*)d_in[14];
  const float* W3  = (const float*)d_in[15];
  const float* a3s = (const float*)d_in[16];
  const float* a3d = (const float*)d_in[17];
  const float* b3  = (const float*)d_in[18];
  const float* g3  = (const float*)d_in[19];
  const float* be3 = (const float*)d_in[20];
  const float* Wg  = (const float*)d_in[21];
  const float* bg  = (const float*)d_in[22];
  const float* Wg2 = (const float*)d_in[23];
  const float* bg2 = (const float*)d_in[24];
  const float* Wo  = (const float*)d_in[25];
  const float* bo  = (const float*)d_in[26];

  int N = in_sizes[2];
  int E = in_sizes[1] / 2;
  const int ET = E + N;  // with self-loops
  const int G = 64;
  const int NB = (N + 1023) / 1024;

  // workspace carve-up (256B aligned)
  char* ws = (char*)d_ws;
  size_t off = 0;
  auto carve = [&](size_t bytes) {
    void* p = ws + off;
    off = (off + bytes + 255) & ~(size_t)255;
    return p;
  };
  int* counts    = (int*)carve((size_t)N * 4);
  int* offsets   = (int*)carve((size_t)(N + 1) * 4);
  int* cursor    = (int*)carve((size_t)N * 4);
  int* blocksums = (int*)carve((size_t)NB * 4);
  int* src_csr   = (int*)carve((size_t)ET * 4);
  float* asrc    = (float*)carve((size_t)N * 4 * 4);
  float* adst    = (float*)carve((size_t)N * 4 * 4);
  _Float16* x16  = (_Float16*)carve((size_t)N * 128 * 2);
  _Float16* a16  = (_Float16*)carve((size_t)N * 256 * 2);
  _Float16* h16  = (_Float16*)carve((size_t)N * 256 * 2);
  float* buf3    = (float*)carve((size_t)N * 64 * 4);
  _Float16* Wt1  = (_Float16*)carve((size_t)128 * 256 * 2);
  _Float16* Wt2  = (_Float16*)carve((size_t)256 * 256 * 2);
  _Float16* Wt3  = (_Float16*)carve((size_t)256 * 64 * 2);
  (void)ws_size;

  const int ngrid2 = (N + 1) / 2;
  const int mblocks = (N + 127) / 128;
  const int ncvt = (N * 16 + 255) / 256;

  // --- fused pre-pass (W transposes + x16) ---
  prep_kernel<<<576 + ncvt, 256, 0, stream>>>(W1, W2, W3, x, Wt1, Wt2, Wt3, x16, N * 16);

  // --- single cooperative CSR build ---
  {
    void* args[] = {(void*)&ei, (void*)&E, (void*)&N, (void*)&counts, (void*)&offsets,
                    (void*)&cursor, (void*)&blocksums, (void*)&src_csr};
    hipLaunchCooperativeKernel((void*)csr_coop_kernel, dim3(256), dim3(256), args, 0, stream);
  }

  // --- layer 1 ---
  gemm16_kernel<16, 4><<<mblocks, 256, 0, stream>>>(x16, Wt1, a1s, a1d, h16, asrc, adst, N, 128);
  agg4_ln_kernel<<<ngrid2, 128, 0, stream>>>(h16, asrc, adst, offsets, src_csr, b1, g1, be1, a16, N);

  // --- layer 2 ---
  gemm16_kernel<16, 4><<<mblocks, 256, 0, stream>>>(a16, Wt2, a2s, a2d, h16, asrc, adst, N, 256);
  agg4_ln_kernel<<<ngrid2, 128, 0, stream>>>(h16, asrc, adst, offsets, src_csr, b2, g2, be2, a16, N);

  // --- layer 3 (H=1, C=64) ---
  gemm16_kernel<4, 1><<<mblocks, 256, 0, stream>>>(a16, Wt3, a3s, a3d, h16, asrc, adst, N, 256);
  agg1_ln_kernel<<<ngrid2, 128, 0, stream>>>(h16, asrc, adst, offsets, src_csr, b3, g3, be3, buf3, N);

  // --- fused pool + MLP head ---
  graph_head_kernel<<<G, 1024, 0, stream>>>(buf3, batch, N, Wg, bg, Wg2, bg2, Wo, bo,
                                            (float*)d_out);
}

// Round 13
// 358.941 us; speedup vs baseline: 1.3432x; 1.3432x over previous
//
#include <hip/hip_runtime.h>
#include <math.h>

typedef _Float16 half2v __attribute__((ext_vector_type(2)));
typedef _Float16 half4v __attribute__((ext_vector_type(4)));
typedef _Float16 half8v __attribute__((ext_vector_type(8)));
typedef float floatx4 __attribute__((ext_vector_type(4)));

static __device__ __forceinline__ half2v pack_rtz(float a, float b) {
  return __builtin_bit_cast(half2v, __builtin_amdgcn_cvt_pkrtz(a, b));
}
static __device__ __forceinline__ float dot2(half2v w, unsigned hi, unsigned lo, unsigned sel, float acc) {
  return __builtin_amdgcn_fdot2(w, __builtin_bit_cast(half2v, __builtin_amdgcn_perm(hi, lo, sel)), acc, false);
}

// ------- fused pre-pass: W transposes + x conversion + edge count -------
__global__ __launch_bounds__(256) void prep_kernel(const float* __restrict__ W1,
                                                   const float* __restrict__ W2,
                                                   const float* __restrict__ W3,
                                                   const float* __restrict__ x,
                                                   _Float16* __restrict__ Wt1,
                                                   _Float16* __restrict__ Wt2,
                                                   _Float16* __restrict__ Wt3,
                                                   _Float16* __restrict__ x16, int n8,
                                                   const int* __restrict__ ei, int E, int N,
                                                   int* __restrict__ counts, int ncvt) {
  int b = blockIdx.x;
  int t = threadIdx.x;
  if (b < 256) {                       // Wt1 [256][128] <- W1 [128][256]
    if (t < 128) Wt1[(size_t)b * 128 + t] = (_Float16)W1[(size_t)t * 256 + b];
  } else if (b < 512) {                // Wt2 [256][256] <- W2 [256][256]
    int col = b - 256;
    Wt2[(size_t)col * 256 + t] = (_Float16)W2[(size_t)t * 256 + col];
  } else if (b < 576) {                // Wt3 [64][256] <- W3 [256][64]
    int col = b - 512;
    Wt3[(size_t)col * 256 + t] = (_Float16)W3[(size_t)t * 64 + col];
  } else if (b < 576 + ncvt) {         // x -> x16 (8 elems/thread)
    int i = (b - 576) * 256 + t;
    if (i < n8) {
      float4 a = ((const float4*)x)[2 * i];
      float4 c = ((const float4*)x)[2 * i + 1];
      half8v h = {(_Float16)a.x, (_Float16)a.y, (_Float16)a.z, (_Float16)a.w,
                  (_Float16)c.x, (_Float16)c.y, (_Float16)c.z, (_Float16)c.w};
      ((half8v*)x16)[i] = h;
    }
  } else {                             // edge degree count
    int e = (b - 576 - ncvt) * 256 + t;
    if (e < E + N) {
      int d = (e < E) ? ei[E + e] : (e - E);
      atomicAdd(&counts[d], 1);
    }
  }
}

// ---------------- CSR build ----------------
__global__ __launch_bounds__(1024) void scan1_kernel(const int* __restrict__ counts,
                                                     int* __restrict__ offsets,
                                                     int* __restrict__ blocksums, int n) {
  __shared__ int wsum[16];
  int tid = threadIdx.x, lane = tid & 63, wid = tid >> 6;
  int i = blockIdx.x * 1024 + tid;
  int v = (i < n) ? counts[i] : 0;
  int x = v;
  #pragma unroll
  for (int off = 1; off < 64; off <<= 1) {
    int t = __shfl_up(x, off);
    if (lane >= off) x += t;
  }
  if (lane == 63) wsum[wid] = x;
  __syncthreads();
  if (wid == 0) {
    int w = (lane < 16) ? wsum[lane] : 0;
    #pragma unroll
    for (int off = 1; off < 16; off <<= 1) {
      int t = __shfl_up(w, off);
      if (lane >= off) w += t;
    }
    if (lane < 16) wsum[lane] = w;
  }
  __syncthreads();
  int wpre = (wid > 0) ? wsum[wid - 1] : 0;
  if (i < n) offsets[i] = wpre + x - v;
  if (tid == 0) blocksums[blockIdx.x] = wsum[15];
}

__global__ __launch_bounds__(1024) void scan2_kernel(int* __restrict__ blocksums,
                                                     int* __restrict__ offsets, int nb, int n) {
  __shared__ int wsum[16];
  int tid = threadIdx.x, lane = tid & 63, wid = tid >> 6;
  int v = (tid < nb) ? blocksums[tid] : 0;
  int x = v;
  #pragma unroll
  for (int off = 1; off < 64; off <<= 1) {
    int t = __shfl_up(x, off);
    if (lane >= off) x += t;
  }
  if (lane == 63) wsum[wid] = x;
  __syncthreads();
  if (wid == 0) {
    int w = (lane < 16) ? wsum[lane] : 0;
    #pragma unroll
    for (int off = 1; off < 16; off <<= 1) {
      int t = __shfl_up(w, off);
      if (lane >= off) w += t;
    }
    if (lane < 16) wsum[lane] = w;
  }
  __syncthreads();
  int wpre = (wid > 0) ? wsum[wid - 1] : 0;
  if (tid < nb) blocksums[tid] = wpre + x - v;
  if (tid == 0) offsets[n] = wsum[15];
}

__global__ void scan3_kernel(int* __restrict__ offsets, int* __restrict__ cursor,
                             const int* __restrict__ blocksums, int n) {
  int i = blockIdx.x * 256 + threadIdx.x;
  if (i < n) {
    int o = offsets[i] + blocksums[i >> 10];
    offsets[i] = o;
    cursor[i] = o;
  }
}

__global__ void scatter_kernel(const int* __restrict__ ei, int E, int N,
                               int* __restrict__ cursor, int* __restrict__ src_csr) {
  int e = blockIdx.x * 256 + threadIdx.x;
  if (e >= E + N) return;
  int s = (e < E) ? ei[e] : (e - E);
  int d = (e < E) ? ei[E + e] : (e - E);
  int pos = atomicAdd(&cursor[d], 1);
  src_csr[pos] = s;
}

// ---------------- all-f16 MFMA GEMM + fused alpha epilogue ----------------
// Operand-swapped: A-operand = weight cols, B-operand = node rows.
// D mapping: node = lane&15, wcol = ct*16 + (lane>>4)*4 + reg (contiguous half4 stores).
template <int NT, int H>   // Nc = NT*16
__global__ __launch_bounds__(256) void gemm16_kernel(const _Float16* __restrict__ A,
                                                     const _Float16* __restrict__ Wt,
                                                     const float* __restrict__ als,
                                                     const float* __restrict__ ald,
                                                     _Float16* __restrict__ out16,
                                                     float* __restrict__ asrc,
                                                     float* __restrict__ adst,
                                                     int M, int K) {
  constexpr int Nc = NT * 16;
  constexpr int BM = 128, BK = 32;
  constexpr int CPH = NT / H;
  __shared__ _Float16 As[BM][40];
  __shared__ _Float16 Ws[Nc][40];
  int bm = blockIdx.x * BM;
  int tid = threadIdx.x;
  int w = tid >> 6, l = tid & 63;
  int lr = l & 15, lg = l >> 4;

  floatx4 acc[2][NT];
  #pragma unroll
  for (int nf = 0; nf < 2; ++nf)
    #pragma unroll
    for (int ct = 0; ct < NT; ++ct) acc[nf][ct] = (floatx4){0.f, 0.f, 0.f, 0.f};

  for (int k0 = 0; k0 < K; k0 += BK) {
    #pragma unroll
    for (int i = 0; i < 2; ++i) {
      int idx = tid + i * 256;
      int r = idx >> 2, c8 = idx & 3;
      int gr = bm + r;
      half8v hv = {(_Float16)0, (_Float16)0, (_Float16)0, (_Float16)0,
                   (_Float16)0, (_Float16)0, (_Float16)0, (_Float16)0};
      if (gr < M) hv = *(const half8v*)&A[(size_t)gr * K + k0 + c8 * 8];
      *(half8v*)&As[r][c8 * 8] = hv;
    }
    #pragma unroll
    for (int i = 0; i < NT / 4; ++i) {
      int idx = tid + i * 256;
      int col = idx >> 2, c8 = idx & 3;
      *(half8v*)&Ws[col][c8 * 8] = *(const half8v*)&Wt[(size_t)col * K + k0 + c8 * 8];
    }
    __syncthreads();
    half8v b0 = *(half8v*)&As[w * 32 + lr][lg * 8];
    half8v b1 = *(half8v*)&As[w * 32 + 16 + lr][lg * 8];
    #pragma unroll
    for (int ct = 0; ct < NT; ++ct) {
      half8v a = *(half8v*)&Ws[ct * 16 + lr][lg * 8];
      acc[0][ct] = __builtin_amdgcn_mfma_f32_16x16x32_f16(a, b0, acc[0][ct], 0, 0, 0);
      acc[1][ct] = __builtin_amdgcn_mfma_f32_16x16x32_f16(a, b1, acc[1][ct], 0, 0, 0);
    }
    __syncthreads();
  }
  float4 als4[NT], ald4[NT];
  #pragma unroll
  for (int ct = 0; ct < NT; ++ct) {
    als4[ct] = *(const float4*)&als[ct * 16 + lg * 4];
    ald4[ct] = *(const float4*)&ald[ct * 16 + lg * 4];
  }
  #pragma unroll
  for (int nf = 0; nf < 2; ++nf) {
    int node = bm + w * 32 + nf * 16 + lr;
    float ps[H], pd[H];
    #pragma unroll
    for (int hh = 0; hh < H; ++hh) {
      float s = 0.f, d = 0.f;
      #pragma unroll
      for (int c2 = 0; c2 < CPH; ++c2) {
        int ct = hh * CPH + c2;
        s += acc[nf][ct][0] * als4[ct].x + acc[nf][ct][1] * als4[ct].y +
             acc[nf][ct][2] * als4[ct].z + acc[nf][ct][3] * als4[ct].w;
        d += acc[nf][ct][0] * ald4[ct].x + acc[nf][ct][1] * ald4[ct].y +
             acc[nf][ct][2] * ald4[ct].z + acc[nf][ct][3] * ald4[ct].w;
      }
      ps[hh] = s; pd[hh] = d;
    }
    #pragma unroll
    for (int hh = 0; hh < H; ++hh) {
      ps[hh] += __shfl_xor(ps[hh], 16); ps[hh] += __shfl_xor(ps[hh], 32);
      pd[hh] += __shfl_xor(pd[hh], 16); pd[hh] += __shfl_xor(pd[hh], 32);
    }
    if (node < M) {
      if (lg == 0) {
        #pragma unroll
        for (int hh = 0; hh < H; ++hh) asrc[node * H + hh] = ps[hh];
      } else if (lg == 1) {
        #pragma unroll
        for (int hh = 0; hh < H; ++hh) adst[node * H + hh] = pd[hh];
      }
      #pragma unroll
      for (int ct = 0; ct < NT; ++ct) {
        half4v hv = {(_Float16)acc[nf][ct][0], (_Float16)acc[nf][ct][1],
                     (_Float16)acc[nf][ct][2], (_Float16)acc[nf][ct][3]};
        *(half4v*)&out16[(size_t)node * Nc + ct * 16 + lg * 4] = hv;
      }
    }
  }
}

// ---------------- fused score + aggregation + LayerNorm + ELU, H=4 ----------
__global__ __launch_bounds__(128) void agg4_ln_kernel(const _Float16* __restrict__ h16,
                                                      const float* __restrict__ asrc,
                                                      const float* __restrict__ adst,
                                                      const int* __restrict__ offsets,
                                                      const int* __restrict__ src_csr,
                                                      const float* __restrict__ bias,
                                                      const float* __restrict__ g,
                                                      const float* __restrict__ be,
                                                      _Float16* __restrict__ out, int n) {
  int wid = threadIdx.x >> 6, lane = threadIdx.x & 63;
  int node = blockIdx.x * 2 + wid;
  if (node >= n) return;
  int start = offsets[node], end = offsets[node + 1];
  int hl = lane >> 5;
  int l5 = lane & 31;
  int head = l5 >> 3;
  float adh = adst[node * 4 + head];
  const uint4* h4 = (const uint4*)h16;
  const half2v ones = {(_Float16)1.f, (_Float16)1.f};
  float acc[8] = {0.f, 0.f, 0.f, 0.f, 0.f, 0.f, 0.f, 0.f};
  float denom = 0.f;
  int i = start + hl;
  for (; i + 6 < end; i += 8) {
    int s0 = src_csr[i], s1 = src_csr[i + 2], s2 = src_csr[i + 4], s3 = src_csr[i + 6];
    uint4 x0 = h4[(size_t)s0 * 32 + l5];
    uint4 x1 = h4[(size_t)s1 * 32 + l5];
    uint4 x2 = h4[(size_t)s2 * 32 + l5];
    uint4 x3 = h4[(size_t)s3 * 32 + l5];
    float sc0 = asrc[s0 * 4 + head] + adh;
    float sc1 = asrc[s1 * 4 + head] + adh;
    float sc2 = asrc[s2 * 4 + head] + adh;
    float sc3 = asrc[s3 * 4 + head] + adh;
    sc0 = fmaxf(sc0, 0.2f * sc0);
    sc1 = fmaxf(sc1, 0.2f * sc1);
    sc2 = fmaxf(sc2, 0.2f * sc2);
    sc3 = fmaxf(sc3, 0.2f * sc3);
    half2v wa = pack_rtz(__expf(sc0), __expf(sc1));
    half2v wb = pack_rtz(__expf(sc2), __expf(sc3));
    denom = __builtin_amdgcn_fdot2(wa, ones, denom, false);
    denom = __builtin_amdgcn_fdot2(wb, ones, denom, false);
    acc[0] = dot2(wa, x1.x, x0.x, 0x05040100u, acc[0]);
    acc[1] = dot2(wa, x1.x, x0.x, 0x07060302u, acc[1]);
    acc[2] = dot2(wa, x1.y, x0.y, 0x05040100u, acc[2]);
    acc[3] = dot2(wa, x1.y, x0.y, 0x07060302u, acc[3]);
    acc[4] = dot2(wa, x1.z, x0.z, 0x05040100u, acc[4]);
    acc[5] = dot2(wa, x1.z, x0.z, 0x07060302u, acc[5]);
    acc[6] = dot2(wa, x1.w, x0.w, 0x05040100u, acc[6]);
    acc[7] = dot2(wa, x1.w, x0.w, 0x07060302u, acc[7]);
    acc[0] = dot2(wb, x3.x, x2.x, 0x05040100u, acc[0]);
    acc[1] = dot2(wb, x3.x, x2.x, 0x07060302u, acc[1]);
    acc[2] = dot2(wb, x3.y, x2.y, 0x05040100u, acc[2]);
    acc[3] = dot2(wb, x3.y, x2.y, 0x07060302u, acc[3]);
    acc[4] = dot2(wb, x3.z, x2.z, 0x05040100u, acc[4]);
    acc[5] = dot2(wb, x3.z, x2.z, 0x07060302u, acc[5]);
    acc[6] = dot2(wb, x3.w, x2.w, 0x05040100u, acc[6]);
    acc[7] = dot2(wb, x3.w, x2.w, 0x07060302u, acc[7]);
  }
  for (; i + 2 < end; i += 4) {
    int s0 = src_csr[i], s1 = src_csr[i + 2];
    uint4 x0 = h4[(size_t)s0 * 32 + l5];
    uint4 x1 = h4[(size_t)s1 * 32 + l5];
    float sc0 = asrc[s0 * 4 + head] + adh;
    float sc1 = asrc[s1 * 4 + head] + adh;
    sc0 = fmaxf(sc0, 0.2f * sc0);
    sc1 = fmaxf(sc1, 0.2f * sc1);
    half2v wa = pack_rtz(__expf(sc0), __expf(sc1));
    denom = __builtin_amdgcn_fdot2(wa, ones, denom, false);
    acc[0] = dot2(wa, x1.x, x0.x, 0x05040100u, acc[0]);
    acc[1] = dot2(wa, x1.x, x0.x, 0x07060302u, acc[1]);
    acc[2] = dot2(wa, x1.y, x0.y, 0x05040100u, acc[2]);
    acc[3] = dot2(wa, x1.y, x0.y, 0x07060302u, acc[3]);
    acc[4] = dot2(wa, x1.z, x0.z, 0x05040100u, acc[4]);
    acc[5] = dot2(wa, x1.z, x0.z, 0x07060302u, acc[5]);
    acc[6] = dot2(wa, x1.w, x0.w, 0x05040100u, acc[6]);
    acc[7] = dot2(wa, x1.w, x0.w, 0x07060302u, acc[7]);
  }
  if (i < end) {
    int s0 = src_csr[i];
    uint4 x0 = h4[(size_t)s0 * 32 + l5];
    float sc0 = asrc[s0 * 4 + head] + adh;
    sc0 = fmaxf(sc0, 0.2f * sc0);
    half2v wa = pack_rtz(__expf(sc0), 0.f);
    denom = __builtin_amdgcn_fdot2(wa, ones, denom, false);
    acc[0] = dot2(wa, x0.x, x0.x, 0x05040100u, acc[0]);
    acc[1] = dot2(wa, x0.x, x0.x, 0x07060302u, acc[1]);
    acc[2] = dot2(wa, x0.y, x0.y, 0x05040100u, acc[2]);
    acc[3] = dot2(wa, x0.y, x0.y, 0x07060302u, acc[3]);
    acc[4] = dot2(wa, x0.z, x0.z, 0x05040100u, acc[4]);
    acc[5] = dot2(wa, x0.z, x0.z, 0x07060302u, acc[5]);
    acc[6] = dot2(wa, x0.w, x0.w, 0x05040100u, acc[6]);
    acc[7] = dot2(wa, x0.w, x0.w, 0x07060302u, acc[7]);
  }
  #pragma unroll
  for (int j = 0; j < 8; ++j) acc[j] += __shfl_xor(acc[j], 32);
  denom += __shfl_xor(denom, 32);
  float inv = 1.f / denom;
  float o[8];
  float4 b0 = *(const float4*)&bias[l5 * 8];
  float4 b1 = *(const float4*)&bias[l5 * 8 + 4];
  o[0] = acc[0] * inv + b0.x; o[1] = acc[1] * inv + b0.y;
  o[2] = acc[2] * inv + b0.z; o[3] = acc[3] * inv + b0.w;
  o[4] = acc[4] * inv + b1.x; o[5] = acc[5] * inv + b1.y;
  o[6] = acc[6] * inv + b1.z; o[7] = acc[7] * inv + b1.w;
  float s = 0.f;
  #pragma unroll
  for (int j = 0; j < 8; ++j) s += o[j];
  #pragma unroll
  for (int off = 16; off; off >>= 1) s += __shfl_xor(s, off);
  float mu = s * (1.f / 256.f);
  float var = 0.f;
  #pragma unroll
  for (int j = 0; j < 8; ++j) { float d = o[j] - mu; var += d * d; }
  #pragma unroll
  for (int off = 16; off; off >>= 1) var += __shfl_xor(var, off);
  float r = rsqrtf(var * (1.f / 256.f) + 1e-5f);
  float4 g0 = *(const float4*)&g[l5 * 8];
  float4 g1 = *(const float4*)&g[l5 * 8 + 4];
  float4 e0 = *(const float4*)&be[l5 * 8];
  float4 e1 = *(const float4*)&be[l5 * 8 + 4];
  float gg[8] = {g0.x, g0.y, g0.z, g0.w, g1.x, g1.y, g1.z, g1.w};
  float ee[8] = {e0.x, e0.y, e0.z, e0.w, e1.x, e1.y, e1.z, e1.w};
  if (hl == 0) {
    half8v yv;
    #pragma unroll
    for (int j = 0; j < 8; ++j) {
      float t = (o[j] - mu) * r * gg[j] + ee[j];
      t = (t > 0.f) ? t : expm1f(t);
      yv[j] = (_Float16)t;
    }
    *(half8v*)&out[(size_t)node * 256 + l5 * 8] = yv;
  }
}

// ---------------- fused score + aggregation + LayerNorm + ELU, H=1 ----------
__global__ __launch_bounds__(128) void agg1_ln_kernel(const _Float16* __restrict__ h16,
                                                      const float* __restrict__ asrc,
                                                      const float* __restrict__ adst,
                                                      const int* __restrict__ offsets,
                                                      const int* __restrict__ src_csr,
                                                      const float* __restrict__ bias,
                                                      const float* __restrict__ g,
                                                      const float* __restrict__ be,
                                                      float* __restrict__ out, int n) {
  int wid = threadIdx.x >> 6, lane = threadIdx.x & 63;
  int node = blockIdx.x * 2 + wid;
  if (node >= n) return;
  int start = offsets[node], end = offsets[node + 1];
  int qi = lane >> 4;
  int ql = lane & 15;
  float adh = adst[node];
  const uint2* h2 = (const uint2*)h16;
  const half2v ones = {(_Float16)1.f, (_Float16)1.f};
  float acc[4] = {0.f, 0.f, 0.f, 0.f};
  float denom = 0.f;
  int i = start + qi;
  for (; i + 12 < end; i += 16) {
    int s0 = src_csr[i], s1 = src_csr[i + 4], s2 = src_csr[i + 8], s3 = src_csr[i + 12];
    uint2 x0 = h2[(size_t)s0 * 16 + ql];
    uint2 x1 = h2[(size_t)s1 * 16 + ql];
    uint2 x2 = h2[(size_t)s2 * 16 + ql];
    uint2 x3 = h2[(size_t)s3 * 16 + ql];
    float sc0 = asrc[s0] + adh;
    float sc1 = asrc[s1] + adh;
    float sc2 = asrc[s2] + adh;
    float sc3 = asrc[s3] + adh;
    sc0 = fmaxf(sc0, 0.2f * sc0);
    sc1 = fmaxf(sc1, 0.2f * sc1);
    sc2 = fmaxf(sc2, 0.2f * sc2);
    sc3 = fmaxf(sc3, 0.2f * sc3);
    half2v wa = pack_rtz(__expf(sc0), __expf(sc1));
    half2v wb = pack_rtz(__expf(sc2), __expf(sc3));
    denom = __builtin_amdgcn_fdot2(wa, ones, denom, false);
    denom = __builtin_amdgcn_fdot2(wb, ones, denom, false);
    acc[0] = dot2(wa, x1.x, x0.x, 0x05040100u, acc[0]);
    acc[1] = dot2(wa, x1.x, x0.x, 0x07060302u, acc[1]);
    acc[2] = dot2(wa, x1.y, x0.y, 0x05040100u, acc[2]);
    acc[3] = dot2(wa, x1.y, x0.y, 0x07060302u, acc[3]);
    acc[0] = dot2(wb, x3.x, x2.x, 0x05040100u, acc[0]);
    acc[1] = dot2(wb, x3.x, x2.x, 0x07060302u, acc[1]);
    acc[2] = dot2(wb, x3.y, x2.y, 0x05040100u, acc[2]);
    acc[3] = dot2(wb, x3.y, x2.y, 0x07060302u, acc[3]);
  }
  for (; i + 4 < end; i += 8) {
    int s0 = src_csr[i], s1 = src_csr[i + 4];
    uint2 x0 = h2[(size_t)s0 * 16 + ql];
    uint2 x1 = h2[(size_t)s1 * 16 + ql];
    float sc0 = asrc[s0] + adh;
    float sc1 = asrc[s1] + adh;
    sc0 = fmaxf(sc0, 0.2f * sc0);
    sc1 = fmaxf(sc1, 0.2f * sc1);
    half2v wa = pack_rtz(__expf(sc0), __expf(sc1));
    denom = __builtin_amdgcn_fdot2(wa, ones, denom, false);
    acc[0] = dot2(wa, x1.x, x0.x, 0x05040100u, acc[0]);
    acc[1] = dot2(wa, x1.x, x0.x, 0x07060302u, acc[1]);
    acc[2] = dot2(wa, x1.y, x0.y, 0x05040100u, acc[2]);
    acc[3] = dot2(wa, x1.y, x0.y, 0x07060302u, acc[3]);
  }
  if (i < end) {
    int s0 = src_csr[i];
    uint2 x0 = h2[(size_t)s0 * 16 + ql];
    float sc0 = asrc[s0] + adh;
    sc0 = fmaxf(sc0, 0.2f * sc0);
    half2v wa = pack_rtz(__expf(sc0), 0.f);
    denom = __builtin_amdgcn_fdot2(wa, ones, denom, false);
    acc[0] = dot2(wa, x0.x, x0.x, 0x05040100u, acc[0]);
    acc[1] = dot2(wa, x0.x, x0.x, 0x07060302u, acc[1]);
    acc[2] = dot2(wa, x0.y, x0.y, 0x05040100u, acc[2]);
    acc[3] = dot2(wa, x0.y, x0.y, 0x07060302u, acc[3]);
  }
  #pragma unroll
  for (int off = 32; off >= 16; off >>= 1) {
    #pragma unroll
    for (int j = 0; j < 4; ++j) acc[j] += __shfl_xor(acc[j], off);
    denom += __shfl_xor(denom, off);
  }
  float inv = 1.f / denom;
  float4 b4 = *(const float4*)&bias[ql * 4];
  float o[4];
  o[0] = acc[0] * inv + b4.x; o[1] = acc[1] * inv + b4.y;
  o[2] = acc[2] * inv + b4.z; o[3] = acc[3] * inv + b4.w;
  float s = o[0] + o[1] + o[2] + o[3];
  #pragma unroll
  for (int off = 8; off; off >>= 1) s += __shfl_xor(s, off);
  float mu = s * (1.f / 64.f);
  float var = 0.f;
  #pragma unroll
  for (int j = 0; j < 4; ++j) { float d = o[j] - mu; var += d * d; }
  #pragma unroll
  for (int off = 8; off; off >>= 1) var += __shfl_xor(var, off);
  float r = rsqrtf(var * (1.f / 64.f) + 1e-5f);
  float4 g4 = *(const float4*)&g[ql * 4];
  float4 e4 = *(const float4*)&be[ql * 4];
  float gg[4] = {g4.x, g4.y, g4.z, g4.w};
  float ee[4] = {e4.x, e4.y, e4.z, e4.w};
  float y[4];
  #pragma unroll
  for (int j = 0; j < 4; ++j) {
    float t = (o[j] - mu) * r * gg[j] + ee[j];
    y[j] = (t > 0.f) ? t : expm1f(t);
  }
  if (qi == 0) {
    *(float4*)&out[(size_t)node * 64 + ql * 4] = make_float4(y[0], y[1], y[2], y[3]);
  }
}

// ---------------- fused pool + MLP head (batch sorted; 1024-thr pool) --------
__global__ __launch_bounds__(1024) void graph_head_kernel(const float* __restrict__ h,
                                                          const int* __restrict__ batch, int N,
                                                          const float* __restrict__ Wg,
                                                          const float* __restrict__ bg,
                                                          const float* __restrict__ Wg2,
                                                          const float* __restrict__ bg2,
                                                          const float* __restrict__ Wo,
                                                          const float* __restrict__ bo,
                                                          float* __restrict__ out) {
  __shared__ int bounds[2];
  __shared__ float part[64][16][4];
  __shared__ float gm[64];
  __shared__ float z1[128];
  __shared__ float z2[64];
  int g = blockIdx.x;
  int tid = threadIdx.x;
  if (tid < 2) {
    int target = g + tid;
    int lo = 0, hi = N;
    while (lo < hi) {
      int mid = (lo + hi) >> 1;
      if (batch[mid] < target) lo = mid + 1; else hi = mid;
    }
    bounds[tid] = lo;
  }
  __syncthreads();
  int lo = bounds[0], hi = bounds[1];
  int sub = tid >> 4, cq = tid & 15;
  float4 acc = make_float4(0.f, 0.f, 0.f, 0.f);
  for (int r = lo + sub; r < hi; r += 64) {
    float4 v = *(const float4*)&h[(size_t)r * 64 + cq * 4];
    acc.x += v.x; acc.y += v.y; acc.z += v.z; acc.w += v.w;
  }
  part[sub][cq][0] = acc.x; part[sub][cq][1] = acc.y;
  part[sub][cq][2] = acc.z; part[sub][cq][3] = acc.w;
  __syncthreads();
  #pragma unroll
  for (int st = 32; st >= 1; st >>= 1) {
    if (sub < st) {
      #pragma unroll
      for (int j = 0; j < 4; ++j) part[sub][cq][j] += part[sub + st][cq][j];
    }
    __syncthreads();
  }
  if (tid < 16) {
    float invc = 1.f / fmaxf((float)(hi - lo), 1.f);
    #pragma unroll
    for (int j = 0; j < 4; ++j) gm[tid * 4 + j] = part[0][tid][j] * invc;
  }
  __syncthreads();
  if (tid < 128) {
    float a = bg[tid];
    for (int k = 0; k < 64; ++k) a += gm[k] * Wg[k * 128 + tid];
    z1[tid] = fmaxf(a, 0.f);
  }
  __syncthreads();
  if (tid < 64) {
    float a = bg2[tid];
    for (int k = 0; k < 128; ++k) a += z1[k] * Wg2[k * 64 + tid];
    z2[tid] = fmaxf(a, 0.f);
  }
  __syncthreads();
  if (tid < 5) {
    float a = bo[tid];
    for (int k = 0; k < 64; ++k) a += z2[k] * Wo[k * 5 + tid];
    out[g * 5 + tid] = a;
  }
}

// ---------------- launch ----------------
extern "C" void kernel_launch(void* const* d_in, const int* in_sizes, int n_in,
                              void* d_out, int out_size, void* d_ws, size_t ws_size,
                              hipStream_t stream) {
  const float* x   = (const float*)d_in[0];
  const int* ei    = (const int*)d_in[1];
  const int* batch = (const int*)d_in[2];
  const float* W1  = (const float*)d_in[3];
  const float* a1s = (const float*)d_in[4];
  const float* a1d = (const float*)d_in[5];
  const float* b1  = (const float*)d_in[6];
  const float* g1  = (const float*)d_in[7];
  const float* be1 = (const float*)d_in[8];
  const float* W2  = (const float*)d_in[9];
  const float* a2s = (const float*)d_in[10];
  const float* a2d = (const float*)d_in[11];
  const float* b2  = (const float*)d_in[12];
  const float* g2  = (const float*)d_in[13];
  const float* be2 = (const float*)d_in[14];
  const float* W3  = (const float*)d_in[15];
  const float* a3s = (const float*)d_in[16];
  const float* a3d = (const float*)d_in[17];
  const float* b3  = (const float*)d_in[18];
  const float* g3  = (const float*)d_in[19];
  const float* be3 = (const float*)d_in[20];
  const float* Wg  = (const float*)d_in[21];
  const float* bg  = (const float*)d_in[22];
  const float* Wg2 = (const float*)d_in[23];
  const float* bg2 = (const float*)d_in[24];
  const float* Wo  = (const float*)d_in[25];
  const float* bo  = (const float*)d_in[26];

  const int N = in_sizes[2];
  const int E = in_sizes[1] / 2;
  const int ET = E + N;  // with self-loops
  const int G = 64;
  const int NB = (N + 1023) / 1024;

  // workspace carve-up (256B aligned)
  char* ws = (char*)d_ws;
  size_t off = 0;
  auto carve = [&](size_t bytes) {
    void* p = ws + off;
    off = (off + bytes + 255) & ~(size_t)255;
    return p;
  };
  int* counts    = (int*)carve((size_t)N * 4);
  int* offsets   = (int*)carve((size_t)(N + 1) * 4);
  int* cursor    = (int*)carve((size_t)N * 4);
  int* blocksums = (int*)carve((size_t)NB * 4);
  int* src_csr   = (int*)carve((size_t)ET * 4);
  float* asrc    = (float*)carve((size_t)N * 4 * 4);
  float* adst    = (float*)carve((size_t)N * 4 * 4);
  _Float16* x16  = (_Float16*)carve((size_t)N * 128 * 2);
  _Float16* a16  = (_Float16*)carve((size_t)N * 256 * 2);
  _Float16* h16  = (_Float16*)carve((size_t)N * 256 * 2);
  float* buf3    = (float*)carve((size_t)N * 64 * 4);
  _Float16* Wt1  = (_Float16*)carve((size_t)128 * 256 * 2);
  _Float16* Wt2  = (_Float16*)carve((size_t)256 * 256 * 2);
  _Float16* Wt3  = (_Float16*)carve((size_t)256 * 64 * 2);
  (void)ws_size;

  const int egrid = (ET + 255) / 256;
  const int ngrid2 = (N + 1) / 2;
  const int mblocks = (N + 127) / 128;
  const int ncvt = (N * 16 + 255) / 256;

  // --- memset, then fused pre-pass (W transposes + x16 + edge count) ---
  hipMemsetAsync(counts, 0, (size_t)N * 4, stream);
  prep_kernel<<<576 + ncvt + egrid, 256, 0, stream>>>(W1, W2, W3, x, Wt1, Wt2, Wt3,
                                                      x16, N * 16, ei, E, N, counts, ncvt);

  // --- CSR (dst-sorted src list) ---
  scan1_kernel<<<NB, 1024, 0, stream>>>(counts, offsets, blocksums, N);
  scan2_kernel<<<1, 1024, 0, stream>>>(blocksums, offsets, NB, N);
  scan3_kernel<<<(N + 255) / 256, 256, 0, stream>>>(offsets, cursor, blocksums, N);
  scatter_kernel<<<egrid, 256, 0, stream>>>(ei, E, N, cursor, src_csr);

  // --- layer 1 ---
  gemm16_kernel<16, 4><<<mblocks, 256, 0, stream>>>(x16, Wt1, a1s, a1d, h16, asrc, adst, N, 128);
  agg4_ln_kernel<<<ngrid2, 128, 0, stream>>>(h16, asrc, adst, offsets, src_csr, b1, g1, be1, a16, N);

  // --- layer 2 ---
  gemm16_kernel<16, 4><<<mblocks, 256, 0, stream>>>(a16, Wt2, a2s, a2d, h16, asrc, adst, N, 256);
  agg4_ln_kernel<<<ngrid2, 128, 0, stream>>>(h16, asrc, adst, offsets, src_csr, b2, g2, be2, a16, N);

  // --- layer 3 (H=1, C=64) ---
  gemm16_kernel<4, 1><<<mblocks, 256, 0, stream>>>(a16, Wt3, a3s, a3d, h16, asrc, adst, N, 256);
  agg1_ln_kernel<<<ngrid2, 128, 0, stream>>>(h16, asrc, adst, offsets, src_csr, b3, g3, be3, buf3, N);

  // --- fused pool + MLP head ---
  graph_head_kernel<<<G, 1024, 0, stream>>>(buf3, batch, N, Wg, bg, Wg2, bg2, Wo, bo,
                                            (float*)d_out);
}